// Round 5
// baseline (383.726 us; speedup 1.0000x reference)
//
#include <hip/hip_runtime.h>

typedef __bf16 bf16;
typedef __bf16 bf16x8 __attribute__((ext_vector_type(8)));
typedef float f32x16 __attribute__((ext_vector_type(16)));

#define B_ROWS 16384
#define N_DIM  4096
#define K_DIM  128

// ---------------------------------------------------------------------------
// Kernel 1: transpose V (4096x128 f32) -> Ut (128x4096 bf16), fused with
// per-column partial sums (for s = V.sum(0)).  (unchanged, proven)
// ---------------------------------------------------------------------------
__global__ __launch_bounds__(256) void prep_kernel(const float* __restrict__ V,
                                                   float* __restrict__ spart,
                                                   bf16* __restrict__ Ut) {
    __shared__ bf16 tile[128 * 136];
    __shared__ float sp[256];
    const int t = threadIdx.x;
    const int jbase = blockIdx.x * 128;
    const int c  = t & 127;
    const int j0 = t >> 7;

    float sacc = 0.f;
#pragma unroll 8
    for (int i = 0; i < 64; ++i) {
        int j = j0 + 2 * i;
        float v = V[(size_t)(jbase + j) * K_DIM + c];
        sacc += v;
        tile[c * 136 + j] = (bf16)v;
    }
    sp[t] = sacc;
    __syncthreads();
    if (t < 128) spart[blockIdx.x * 128 + t] = sp[t] + sp[t + 128];

    const int col = t >> 1, half = t & 1;
#pragma unroll
    for (int i = 0; i < 4; ++i) {
        uint4 d = *(const uint4*)&tile[col * 136 + half * 64 + i * 16];
        *(uint4*)&Ut[(size_t)col * N_DIM + jbase + half * 64 + i * 16] = d;
    }
}

// ---------------------------------------------------------------------------
// Kernel 2 (main): BM=16, 1024 blocks, 256 thr = 4 waves, 40960 B LDS
// => 4 blocks/CU (16 waves/CU, 2x round-4) to interleave the per-epoch
// load bursts (round-4 diagnosis: HBM at 47% because residency was
// grid-capped at 2 blocks/CU).
// MFMA stays 32x32: A rows clamped (l31&15) -> rows 16-31 are duplicates,
// never read back.  us = two fixed half-buffers (K 0-63 / 64-127),
// wave-private, refilled in place after each half's MFMA cluster with
// per-wave counted vmcnt(8) (DS in-order retirement makes in-place safe).
// Barrier stays 1/epoch (only xs is cross-wave), 32 epochs.
// ---------------------------------------------------------------------------
__global__ __launch_bounds__(256, 4) void fm_main(const float* __restrict__ x,
                                                  const float* __restrict__ W,
                                                  const float* __restrict__ bptr,
                                                  const bf16* __restrict__ Ut,
                                                  const float* __restrict__ spart,
                                                  float* __restrict__ out) {
    __shared__ __align__(16) char pool[40960];
    bf16* xs = (bf16*)pool;               // 2 bufs x 16 x 128 = 4096 elems (8 KB)
    bf16* us = (bf16*)(pool + 8192);      // 2 halves x 128 x 64 = 16384 elems (32 KB)

    const int t    = threadIdx.x;
    const int wave = t >> 6;
    const int lane = t & 63;
    const int l31  = lane & 31;
    const int h    = lane >> 5;
    const int r0   = blockIdx.x * 16;

    const int srow = t >> 4;              // 0..15 x row
    const int scg  = t & 15;              // 0..15 chunk of 8 floats

    f32x16 acc;
#pragma unroll
    for (int i = 0; i < 16; ++i) acc[i] = 0.f;

    float xsum_acc = 0.f, xw_acc = 0.f;
    const float* xrow = x + (size_t)(r0 + srow) * N_DIM + scg * 8;
    const float* wrow = W + scg * 8;
    // DMA lane mapping (per half, 4 instrs): instr j covers local rows
    // j*8+(lane>>3), phys chunk lane&7; source logical chunk pre-swizzled.
    const int drw = lane >> 3;            // 0..7 row-sub within DMA group
    const int dch = lane & 7;             // phys chunk

    // ---- prologue: regs tile 0 FIRST, then DMA(0,H0), DMA(0,H1) ----
    float4 a0 = *(const float4*)(xrow);
    float4 a1 = *(const float4*)(xrow + 4);
    float4 w0 = *(const float4*)(wrow);
    float4 w1 = *(const float4*)(wrow + 4);
    __builtin_amdgcn_sched_barrier(0);
#pragma unroll
    for (int hs = 0; hs < 2; ++hs) {
#pragma unroll
        for (int j = 0; j < 4; ++j) {
            const int rw = j * 8 + drw;
            const bf16* src = Ut + (size_t)(wave * 32 + rw) * N_DIM + hs * 64
                                 + (size_t)((dch ^ (rw & 7)) * 8);
            __builtin_amdgcn_global_load_lds(
                (const __attribute__((address_space(1))) void*)src,
                (__attribute__((address_space(3))) void*)&us[hs * 8192 + (wave * 32 + j * 8) * 64],
                16, 0, 0);
        }
    }
    __builtin_amdgcn_sched_barrier(0);

#pragma unroll 2
    for (int it = 0; it < 32; ++it) {
        const int bsel = it & 1;
        const int kb1 = ((it < 31) ? (it + 1) : 0) * 128;   // clamp: harmless

        // ---- store x regs (tile it) into xs[bsel], XOR-16 swizzled ----
        bf16x8 xb;
        xb[0] = (bf16)a0.x; xb[1] = (bf16)a0.y; xb[2] = (bf16)a0.z; xb[3] = (bf16)a0.w;
        xb[4] = (bf16)a1.x; xb[5] = (bf16)a1.y; xb[6] = (bf16)a1.z; xb[7] = (bf16)a1.w;
        *(bf16x8*)&xs[bsel * 2048 + srow * 128 + ((scg ^ srow) * 8)] = xb;

        asm volatile("s_waitcnt lgkmcnt(0)" ::: "memory");
        __builtin_amdgcn_s_barrier();
        __builtin_amdgcn_sched_barrier(0);

        // ---- reg prefetch tile it+1 (4 VMEM) ----
        float4 n0 = *(const float4*)(xrow + kb1);
        float4 n1 = *(const float4*)(xrow + kb1 + 4);
        float4 m0 = *(const float4*)(wrow + kb1);
        float4 m1 = *(const float4*)(wrow + kb1 + 4);
        __builtin_amdgcn_sched_barrier(0);

        // ---- exact fp32 side sums on tile-it regs ----
        xsum_acc += (a0.x + a0.y + a0.z + a0.w) + (a1.x + a1.y + a1.z + a1.w);
        xw_acc   += a0.x * w0.x + a0.y * w0.y + a0.z * w0.z + a0.w * w0.w
                  + a1.x * w1.x + a1.y * w1.y + a1.z * w1.z + a1.w * w1.w;
        __builtin_amdgcn_sched_barrier(0);

        // ---- H0: wait DMA(it,H0) [8 newer: DMA(it,H1)4 + regs4], MFMA ----
        asm volatile("s_waitcnt vmcnt(8)" ::: "memory");
        __builtin_amdgcn_sched_barrier(0);
        __builtin_amdgcn_s_setprio(1);
#pragma unroll
        for (int ks = 0; ks < 64; ks += 16) {
            const int ch = (ks >> 3) + h;                  // 0..7
            bf16x8 af  = *(const bf16x8*)&xs[bsel * 2048 + (l31 & 15) * 128 + ((ch ^ (l31 & 15)) * 8)];
            bf16x8 bfv = *(const bf16x8*)&us[(wave * 32 + l31) * 64 + ((ch ^ (l31 & 7)) * 8)];
            acc = __builtin_amdgcn_mfma_f32_32x32x16_bf16(af, bfv, acc, 0, 0, 0);
        }
        __builtin_amdgcn_s_setprio(0);
        __builtin_amdgcn_sched_barrier(0);
        // refill H0 with tile it+1 (all our H0 ds_reads retired: DS in-order)
#pragma unroll
        for (int j = 0; j < 4; ++j) {
            const int rw = j * 8 + drw;
            const bf16* src = Ut + (size_t)(wave * 32 + rw) * N_DIM + kb1
                                 + (size_t)((dch ^ (rw & 7)) * 8);
            __builtin_amdgcn_global_load_lds(
                (const __attribute__((address_space(1))) void*)src,
                (__attribute__((address_space(3))) void*)&us[(wave * 32 + j * 8) * 64],
                16, 0, 0);
        }
        __builtin_amdgcn_sched_barrier(0);

        // ---- H1: wait DMA(it,H1) [8 newer: regs4 + DMA(it+1,H0)4], MFMA ----
        asm volatile("s_waitcnt vmcnt(8)" ::: "memory");
        __builtin_amdgcn_sched_barrier(0);
        __builtin_amdgcn_s_setprio(1);
#pragma unroll
        for (int ks = 64; ks < 128; ks += 16) {
            const int ch = (ks >> 3) + h;                  // 8..15
            const int c8 = ch & 7;                         // 0..7 within half
            bf16x8 af  = *(const bf16x8*)&xs[bsel * 2048 + (l31 & 15) * 128 + ((ch ^ (l31 & 15)) * 8)];
            bf16x8 bfv = *(const bf16x8*)&us[8192 + (wave * 32 + l31) * 64 + ((c8 ^ (l31 & 7)) * 8)];
            acc = __builtin_amdgcn_mfma_f32_32x32x16_bf16(af, bfv, acc, 0, 0, 0);
        }
        __builtin_amdgcn_s_setprio(0);
        __builtin_amdgcn_sched_barrier(0);
        // refill H1 with tile it+1
#pragma unroll
        for (int j = 0; j < 4; ++j) {
            const int rw = j * 8 + drw;
            const bf16* src = Ut + (size_t)(wave * 32 + rw) * N_DIM + kb1 + 64
                                 + (size_t)((dch ^ (rw & 7)) * 8);
            __builtin_amdgcn_global_load_lds(
                (const __attribute__((address_space(1))) void*)src,
                (__attribute__((address_space(3))) void*)&us[8192 + (wave * 32 + j * 8) * 64],
                16, 0, 0);
        }
        __builtin_amdgcn_sched_barrier(0);

        a0 = n0; a1 = n1; w0 = m0; w1 = m1;
    }

    // ---- epilogue (aliases pool after full drain) ----
    __syncthreads();   // all LDS reads done; drains tail VMEM
    float* redxs  = (float*)pool;           // 256 f
    float* redxw  = redxs + 256;            // 256 f
    float* rowsq  = redxw + 256;            // 64 f
    float* snred  = rowsq + 64;             // 2 f

    redxs[t] = xsum_acc;
    redxw[t] = xw_acc;

    // per-row sum of squares over this wave's 32 cols; only C rows 0..15
    // are real (A rows 16-31 were clamped duplicates).
    // C/D layout: col = lane&31, row = (reg&3) + 8*(reg>>2) + 4*(lane>>5)
#pragma unroll
    for (int r = 0; r < 8; ++r) {
        float s = acc[r] * acc[r];
        s += __shfl_xor(s, 1);
        s += __shfl_xor(s, 2);
        s += __shfl_xor(s, 4);
        s += __shfl_xor(s, 8);
        s += __shfl_xor(s, 16);
        if (l31 == 0) {
            int row = (r & 3) + 8 * (r >> 2) + 4 * h;      // 0..15
            rowsq[wave * 16 + row] = s;
        }
    }

    // snorm = ||V.sum(0)||^2 from spart (32x128, L2-resident)
    if (t < 128) {
        float sv = 0.f;
#pragma unroll
        for (int bb = 0; bb < 32; ++bb) sv += spart[bb * 128 + t];
        float sq = sv * sv;
#pragma unroll
        for (int m = 32; m >= 1; m >>= 1) sq += __shfl_down(sq, m, 64);
        if ((t & 63) == 0) snred[t >> 6] = sq;
    }
    __syncthreads();

    if (t < 16) {
        float xsum = 0.f, xw = 0.f;
#pragma unroll
        for (int g = 0; g < 16; ++g) { xsum += redxs[t * 16 + g]; xw += redxw[t * 16 + g]; }
        float sq = rowsq[t] + rowsq[16 + t] + rowsq[32 + t] + rowsq[48 + t];
        float snorm = snred[0] + snred[1];
        float bv = bptr[0];
        out[r0 + t] = bv + xw + 0.5f * sq - 0.5f * xsum * xsum * snorm;
    }
}

// ---------------------------------------------------------------------------
extern "C" void kernel_launch(void* const* d_in, const int* in_sizes, int n_in,
                              void* d_out, int out_size, void* d_ws, size_t ws_size,
                              hipStream_t stream) {
    const float* x  = (const float*)d_in[0];
    const float* W  = (const float*)d_in[1];
    const float* bp = (const float*)d_in[2];
    const float* V  = (const float*)d_in[3];
    float* out = (float*)d_out;

    char* ws = (char*)d_ws;
    float* spart = (float*)(ws + 1024);        // 16 KB
    bf16*  Ut    = (bf16*)(ws + 32768);        // 1 MB

    hipLaunchKernelGGL(prep_kernel, dim3(32), dim3(256), 0, stream, V, spart, Ut);
    hipLaunchKernelGGL(fm_main, dim3(1024), dim3(256), 0, stream, x, W, bp, Ut, spart, out);
}